// Round 2
// baseline (804.540 us; speedup 1.0000x reference)
//
#include <hip/hip_runtime.h>

typedef __attribute__((ext_vector_type(8))) short short8;
typedef __attribute__((ext_vector_type(4))) float floatx4;

// f32 -> bf16 round-to-nearest-even (inputs are finite; no NaN guard needed)
__device__ __forceinline__ short f2bf(float f) {
    unsigned int u = __float_as_uint(f);
    u = (u + 0x7FFFu + ((u >> 16) & 1u)) >> 16;
    return (short)u;
}

// ---------------- CSR build ----------------

__global__ void zero_i32(int* __restrict__ p, int n) {
    int i = blockIdx.x * blockDim.x + threadIdx.x;
    if (i < n) p[i] = 0;
}

__global__ void count_deg(const int* __restrict__ dst, int* __restrict__ cnt, int E) {
    int e = blockIdx.x * blockDim.x + threadIdx.x;
    if (e < E) atomicAdd(&cnt[dst[e]], 1);
}

// per-1024-chunk sums (256 threads x 4 elems)
__global__ void scan_part(const int* __restrict__ cnt, int* __restrict__ bsums, int N) {
    __shared__ int sh[256];
    int tid = threadIdx.x;
    int base = blockIdx.x * 1024 + tid * 4;
    int s = 0;
#pragma unroll
    for (int j = 0; j < 4; ++j) { int idx = base + j; if (idx < N) s += cnt[idx]; }
    sh[tid] = s; __syncthreads();
    for (int d = 128; d > 0; d >>= 1) { if (tid < d) sh[tid] += sh[tid + d]; __syncthreads(); }
    if (tid == 0) bsums[blockIdx.x] = sh[0];
}

// exclusive scan of up to 1024 block sums, single block of 1024 threads
__global__ void scan_small(int* __restrict__ b, int nb) {
    __shared__ int s[1024];
    int tid = threadIdx.x;
    int v = (tid < nb) ? b[tid] : 0;
    s[tid] = v; __syncthreads();
    for (int d = 1; d < 1024; d <<= 1) {
        int t = (tid >= d) ? s[tid - d] : 0;
        __syncthreads();
        s[tid] += t;
        __syncthreads();
    }
    if (tid < nb) b[tid] = s[tid] - v;
}

__global__ void scan_final(const int* __restrict__ cnt, const int* __restrict__ bsums,
                           int* __restrict__ off, int* __restrict__ cur,
                           float* __restrict__ dinv, int N) {
    __shared__ int sh[256];
    int tid = threadIdx.x;
    int base = blockIdx.x * 1024 + tid * 4;
    int v[4]; int tsum = 0;
#pragma unroll
    for (int j = 0; j < 4; ++j) { int idx = base + j; v[j] = (idx < N) ? cnt[idx] : 0; tsum += v[j]; }
    sh[tid] = tsum; __syncthreads();
    for (int d = 1; d < 256; d <<= 1) {
        int t = (tid >= d) ? sh[tid - d] : 0;
        __syncthreads();
        sh[tid] += t;
        __syncthreads();
    }
    int run = sh[tid] - tsum + bsums[blockIdx.x];
#pragma unroll
    for (int j = 0; j < 4; ++j) {
        int idx = base + j;
        if (idx < N) {
            off[idx] = run;
            cur[idx] = run;
            dinv[idx] = rsqrtf((float)(v[j] + 1));   // deg includes self-loop
            run += v[j];
        }
    }
}

__global__ void fill_edges(const int* __restrict__ eidx, const float* __restrict__ dinv,
                           int* __restrict__ cur, int2* __restrict__ edges, int E) {
    int e = blockIdx.x * blockDim.x + threadIdx.x;
    if (e >= E) return;
    int s = eidx[e];        // src
    int d = eidx[E + e];    // dst
    float nm = dinv[s] * dinv[d];
    int p = atomicAdd(&cur[d], 1);
    edges[p] = make_int2(s, __float_as_int(nm));
}

// ---------------- layer 1 GEMM: h1[N,16] = x[N,512] @ W1[512,16] ----------------
// wave = one 16x16 output tile, mfma_f32_16x16x32_bf16, f32 inputs cvt'd to bf16 in-register.
__global__ __launch_bounds__(256) void gemm1_mfma(const float* __restrict__ x,
                                                  const float* __restrict__ w1,
                                                  float* __restrict__ h1,
                                                  int ntiles, int N) {
    __shared__ __align__(16) float wl[512 * 16];    // 32 KB
    int tid = threadIdx.x;
    for (int i = tid; i < 2048; i += 256)           // 8192 floats = 2048 float4
        ((float4*)wl)[i] = ((const float4*)w1)[i];
    __syncthreads();

    int lane = tid & 63;
    int q = lane >> 4, r = lane & 15;

    // B fragments for all 16 K-iters: lane holds B[k=q*8+j][n=r]
    short8 bf[16];
#pragma unroll
    for (int kk = 0; kk < 16; ++kk) {
        int kb = kk * 32 + q * 8;
        short8 t;
#pragma unroll
        for (int j = 0; j < 8; ++j) t[j] = f2bf(wl[(kb + j) * 16 + r]);
        bf[kk] = t;
    }

    int tile = blockIdx.x * 4 + (tid >> 6);
    if (tile >= ntiles) return;
    int nb = tile * 16;
    int row = nb + r; if (row >= N) row = N - 1;
    const float* xp = x + (size_t)row * 512 + q * 8;   // A[m=r][k=q*8+j]
    floatx4 acc = {0.f, 0.f, 0.f, 0.f};
#pragma unroll
    for (int kk = 0; kk < 16; ++kk) {
        float4 a0 = *(const float4*)(xp + kk * 32);
        float4 a1 = *(const float4*)(xp + kk * 32 + 4);
        short8 af;
        af[0] = f2bf(a0.x); af[1] = f2bf(a0.y); af[2] = f2bf(a0.z); af[3] = f2bf(a0.w);
        af[4] = f2bf(a1.x); af[5] = f2bf(a1.y); af[6] = f2bf(a1.z); af[7] = f2bf(a1.w);
        acc = __builtin_amdgcn_mfma_f32_16x16x32_bf16(af, bf[kk], acc, 0, 0, 0);
    }
    // C/D: col=lane&15, row=(lane>>4)*4+i
#pragma unroll
    for (int i = 0; i < 4; ++i) {
        int rr = nb + q * 4 + i;
        if (rr < N) h1[(size_t)rr * 16 + r] = acc[i];
    }
}

// ---------------- CSR aggregate over 16-dim features ----------------
// 16 lanes per node; lane h owns feature h. out[n] = dinv^2*in[n] + sum norm*in[src] (+bias, relu)
__global__ __launch_bounds__(256) void agg16(const float* __restrict__ in, float* __restrict__ out,
                                             const int* __restrict__ off, const int* __restrict__ cnt,
                                             const float* __restrict__ dinv, const int2* __restrict__ edges,
                                             const float* __restrict__ bias, int relu, int N) {
    int t = blockIdx.x * blockDim.x + threadIdx.x;
    int n = t >> 4;
    if (n >= N) return;
    int h = t & 15;
    float di = dinv[n];
    float acc = di * di * in[n * 16 + h];
    int p0 = off[n];
    int c = cnt[n];
    const int2* ep = edges + p0;
    for (int i = 0; i < c; ++i) {
        int2 e = ep[i];
        acc += __int_as_float(e.y) * in[e.x * 16 + h];
    }
    if (bias) acc += bias[h];
    if (relu) acc = fmaxf(acc, 0.0f);
    out[n * 16 + h] = acc;
}

// ---------------- fused W2 + bias + log_softmax + f32 store ----------------
// one wave per node; lanes 0..39 = classes
__global__ __launch_bounds__(256) void out_ls(const float* __restrict__ a2,
                                              const float* __restrict__ w2,
                                              const float* __restrict__ b2,
                                              float* __restrict__ out, int N) {
    __shared__ float w2s[704];   // 640 used + zero pad so lanes 40..63 read zeros
    __shared__ float b2s[40];
    int tid = threadIdx.x;
    for (int i = tid; i < 704; i += 256) w2s[i] = (i < 640) ? w2[i] : 0.0f;
    if (tid < 40) b2s[tid] = b2[tid];
    __syncthreads();
    int lane = tid & 63;
    int n = blockIdx.x * 4 + (tid >> 6);
    if (n >= N) return;
    const float* ar = a2 + (size_t)n * 16;
    bool act = lane < 40;
    float acc = act ? b2s[lane] : 0.0f;
#pragma unroll
    for (int k = 0; k < 16; ++k) {
        float av = ar[k];                 // wave-uniform broadcast load
        acc += av * w2s[k * 40 + lane];   // zeros for lanes>=40, discarded below
    }
    float v = act ? acc : -__builtin_inff();
#pragma unroll
    for (int s = 32; s > 0; s >>= 1) v = fmaxf(v, __shfl_xor(v, s, 64));
    float ex = act ? expf(acc - v) : 0.0f;
    float ssum = ex;
#pragma unroll
    for (int s = 32; s > 0; s >>= 1) ssum += __shfl_xor(ssum, s, 64);
    float lse = logf(ssum);
    if (act) out[(size_t)n * 40 + lane] = acc - v - lse;
}

// ---------------- launch ----------------

extern "C" void kernel_launch(void* const* d_in, const int* in_sizes, int n_in,
                              void* d_out, int out_size, void* d_ws, size_t ws_size,
                              hipStream_t stream) {
    const float* x   = (const float*)d_in[0];
    const float* W1  = (const float*)d_in[1];
    const float* b1  = (const float*)d_in[2];
    const float* W2  = (const float*)d_in[3];
    const float* b2  = (const float*)d_in[4];
    const int*   eidx = (const int*)d_in[5];
    float* out = (float*)d_out;

    const int N = in_sizes[0] / 512;
    const int E = in_sizes[5] / 2;

    char* w = (char*)d_ws;
    auto alloc = [&](size_t bytes) { char* p = w; w += (bytes + 255) & ~(size_t)255; return p; };
    int*   cnt   = (int*)alloc((size_t)N * 4);
    int*   off   = (int*)alloc((size_t)N * 4);
    int*   cur   = (int*)alloc((size_t)N * 4);
    float* dinv  = (float*)alloc((size_t)N * 4);
    int*   bsums = (int*)alloc(1024 * 4);
    int2*  edges = (int2*)alloc((size_t)E * 8);
    float* h1    = (float*)alloc((size_t)N * 16 * 4);
    float* r1    = (float*)alloc((size_t)N * 16 * 4);
    float* a2    = h1;   // reuse: h1 dead after first agg

    int nb = (N + 1023) / 1024;

    zero_i32<<<(N + 255) / 256, 256, 0, stream>>>(cnt, N);
    count_deg<<<(E + 255) / 256, 256, 0, stream>>>(eidx + E, cnt, E);
    scan_part<<<nb, 256, 0, stream>>>(cnt, bsums, N);
    scan_small<<<1, 1024, 0, stream>>>(bsums, nb);
    scan_final<<<nb, 256, 0, stream>>>(cnt, bsums, off, cur, dinv, N);
    fill_edges<<<(E + 255) / 256, 256, 0, stream>>>(eidx, dinv, cur, edges, E);

    int ntiles = (N + 15) / 16;
    gemm1_mfma<<<(ntiles + 3) / 4, 256, 0, stream>>>(x, W1, h1, ntiles, N);

    agg16<<<((size_t)N * 16 + 255) / 256, 256, 0, stream>>>(h1, r1, off, cnt, dinv, edges, b1, 1, N);
    agg16<<<((size_t)N * 16 + 255) / 256, 256, 0, stream>>>(r1, a2, off, cnt, dinv, edges, (const float*)nullptr, 0, N);

    out_ls<<<(N + 3) / 4, 256, 0, stream>>>(a2, W2, b2, out, N);
}